// Round 9
// baseline (12779.831 us; speedup 1.0000x reference)
//
#include <hip/hip_runtime.h>
#include <hip/hip_bf16.h>

// ws byte layout (dynamic, sized from ws_size at launch):
//   HH ring: R regions @ 0, region stride 139264 B (8192 data words of 16 B
//            {h1[4k..4k+3], h2[4k..4k+3]} per (k4,b) + 8 KB guard gap).
//            Writers: agent-scope atomic dword stores (write-through to MALL).
//            Readers: RING mode (R=32): plain cached loads — a region's
//            addresses were last touched 32 phases ago; ~54 MB/XCD flows
//            through the 4 MB L2 in between, so stale lines are LRU-evicted;
//            first toucher per XCD misses to MALL (fresh), rest hit L2.
//            FALLBACK mode (R=2, ws too small): sc0 sc1 MALL-direct loads (R7).
//   XT:  bf16 [512][64] @ xt_off (65536 B)
//   BAR: @ bar_off, 273 slots x 128 B: leaf[16] | root | mail[256]  (R6 barrier)
//   WP:  f32 [256][128][4][24] @ wp_off (12.6 MB) per-WG packed weights
#define REGION_W 8704              // 16B words per region incl guard
#define BAR_SLOTS 273

typedef __attribute__((ext_vector_type(4))) unsigned int uint4v;

__device__ __forceinline__ float sigm(float x) { return 1.f / (1.f + __expf(-x)); }
__device__ __forceinline__ float tanh_f(float x) {
    float a = fabsf(x);
    float e = __expf(-2.f * a);
    float r = (1.f - e) / (1.f + e);
    return copysignf(r, x);
}
__device__ __forceinline__ float bf2f(unsigned int u) {
    union { unsigned int i; float f; } v; v.i = u << 16; return v.f;
}
__device__ __forceinline__ unsigned short f2bf(float f) {
    union { float f; unsigned int i; } v; v.f = f;
    unsigned int u = v.i + 0x7fffu + ((v.i >> 16) & 1u);   // RNE
    return (unsigned short)(u >> 16);
}

__global__ void init_kernel(const float* __restrict__ x, const float* __restrict__ W0,
                            const float* __restrict__ W1, char* __restrict__ wsb,
                            int R, int xt_off, int bar_off, int wp_off) {
    unsigned int* Hz = (unsigned int*)wsb;
    unsigned short* XT = (unsigned short*)(wsb + xt_off);
    int* BAR = (int*)(wsb + bar_off);
    float* WP = (float*)(wsb + wp_off);
    int i = blockIdx.x * blockDim.x + threadIdx.x;
    int stride = gridDim.x * blockDim.x;
    int hdw = R * REGION_W * 4;
    for (int j = i; j < hdw; j += stride) Hz[j] = 0;
    for (int j = i; j < 32768; j += stride) {
        int p = j >> 6, b = j & 63;
        XT[j] = f2bf(x[b * 512 + p]);
    }
    for (int j = i; j < BAR_SLOTS * 32; j += stride) BAR[j] = 0;
    for (int j = i; j < 256 * 512 * 24; j += stride) {
        int c = j % 24;
        int r = j / 24;            // bx*512 + k
        int k = r & 511;
        int bx = r >> 9;
        int cc = c & 7;
        int col = ((cc >> 1) << 9) + bx * 2 + (cc & 1);
        int mat = c >> 3;
        float v;
        if (mat == 0)      v = W0[(1 + k) * 2048 + col];
        else if (mat == 1) v = W1[k * 2048 + col];
        else               v = W1[(512 + k) * 2048 + col];
        WP[j] = v;
    }
}

// R6 fan-out barrier (proven): leaf RMW -> root RMW -> broadcaster wave stores
// 256 per-WG mailboxes (1 poller/line). All counters MALL-resident.
__device__ __forceinline__ void grid_bar(int* bar, int phase, int bx, int t) {
    __syncthreads();
    if (t < 64) {
        int* leaf = bar + (bx >> 4) * 32;
        int* root = bar + 16 * 32;
        int* mailbase = bar + 17 * 32;
        int target = 16 * (phase + 1);
        int isB = 0;
        if (t == 0) {
            int old = __hip_atomic_fetch_add(leaf, 1, __ATOMIC_RELAXED, __HIP_MEMORY_SCOPE_AGENT);
            if (old == target - 1) {
                int ro = __hip_atomic_fetch_add(root, 1, __ATOMIC_RELAXED, __HIP_MEMORY_SCOPE_AGENT);
                if (ro == target - 1) isB = 1;
            }
        }
        isB = __builtin_amdgcn_readfirstlane(isB);
        if (isB) {
            #pragma unroll
            for (int r = 0; r < 4; ++r)
                __hip_atomic_store(mailbase + (r * 64 + t) * 32, phase + 1,
                                   __ATOMIC_RELAXED, __HIP_MEMORY_SCOPE_AGENT);
        }
        if (t == 0) {
            int* my = mailbase + bx * 32;
            while (__hip_atomic_load(my, __ATOMIC_RELAXED, __HIP_MEMORY_SCOPE_AGENT) < phase + 1)
                __builtin_amdgcn_s_sleep(1);
        }
    }
    __syncthreads();
}

__global__ __launch_bounds__(512) void lstm_kernel(char* __restrict__ wsb,
        const float* __restrict__ W0, const float* __restrict__ b0,
        const float* __restrict__ b1, int Rmask, int ring_mode,
        int xt_off, int bar_off, int wp_off) {
    __shared__ float red[2][8][8][64];   // [layer][wave][c][b], 32 KB

    const int t = threadIdx.x, bx = blockIdx.x;
    const int b = t & 63;
    const int w = __builtin_amdgcn_readfirstlane(t >> 6);    // wave id = k-slice owner

    const uint4v* HH = (const uint4v*)wsb;
    unsigned int* HHw = (unsigned int*)wsb;
    const unsigned short* XT = (const unsigned short*)(wsb + xt_off);
    int* BAR = (int*)(wsb + bar_off);
    const float* wp = (const float*)(wsb + wp_off)
                    + __builtin_amdgcn_readfirstlane(bx * 12288 + (t >> 6) * 1536);

    // cell threads: t<128 -> (layer l = t>>6, batch b); each computes BOTH hu of its pair
    const int cell_l = t >> 6;   // valid for t<128
    float cs0 = 0.f, cs1 = 0.f;
    float bi0 = 0, bi1 = 0, bj0 = 0, bj1 = 0, bf0 = 0, bf1 = 0, bo0 = 0, bo1 = 0;
    float wxi0 = 0, wxi1 = 0, wxj0 = 0, wxj1 = 0, wxf0 = 0, wxf1 = 0, wxo0 = 0, wxo1 = 0;
    if (t < 128) {
        int u0 = bx * 2, u1 = bx * 2 + 1;
        const float* bb = (cell_l == 0) ? b0 : b1;
        bi0 = bb[u0];            bi1 = bb[u1];
        bj0 = bb[512 + u0];      bj1 = bb[512 + u1];
        bf0 = bb[1024 + u0];     bf1 = bb[1024 + u1];
        bo0 = bb[1536 + u0];     bo1 = bb[1536 + u1];
        if (cell_l == 0) {
            wxi0 = W0[u0];          wxi1 = W0[u1];
            wxj0 = W0[512 + u0];    wxj1 = W0[512 + u1];
            wxf0 = W0[1024 + u0];   wxf1 = W0[1024 + u1];
            wxo0 = W0[1536 + u0];   wxo1 = W0[1536 + u1];
        }
    }

    for (int p = 0; p <= 512; ++p) {
        const int ridx = p & Rmask;
        const uint4v* hp = HH + ridx * REGION_W + w * 1024 + b;
        float p1[8] = {0, 0, 0, 0, 0, 0, 0, 0};
        float p2[8] = {0, 0, 0, 0, 0, 0, 0, 0};
        uint4v vv[16];
        if (ring_mode) {
            // plain cached loads: fresh addresses -> L2 miss->MALL for the
            // first toucher per XCD, L2 hits for everyone else
            #pragma unroll
            for (int i = 0; i < 16; ++i) vv[i] = hp[i * 64];
        } else {
            #pragma unroll
            for (int i = 0; i < 16; ++i)
                asm volatile("global_load_dwordx4 %0, %1, off sc0 sc1"
                             : "=v"(vv[i]) : "v"(hp + i * 64));
            asm volatile("s_waitcnt vmcnt(0)" ::: "memory");
        }

        #pragma unroll
        for (int i = 0; i < 16; ++i) {
            unsigned int x0 = vv[i].x, x1 = vv[i].y, x2 = vv[i].z, x3 = vv[i].w;
            float h1v[4] = { bf2f(x0 & 0xffffu), bf2f(x0 >> 16),
                             bf2f(x1 & 0xffffu), bf2f(x1 >> 16) };
            float h2v[4] = { bf2f(x2 & 0xffffu), bf2f(x2 >> 16),
                             bf2f(x3 & 0xffffu), bf2f(x3 >> 16) };
            const float* wk = wp + i * 96;          // wave-uniform -> s_load
            #pragma unroll
            for (int j = 0; j < 4; ++j) {
                const float* wj = wk + j * 24;
                #pragma unroll
                for (int c = 0; c < 8; ++c) {
                    p1[c] += wj[c] * h1v[j];
                    p2[c] += wj[8 + c] * h1v[j] + wj[16 + c] * h2v[j];
                }
            }
        }
        #pragma unroll
        for (int c = 0; c < 8; ++c) {
            red[0][w][c][b] = p1[c];
            red[1][w][c][b] = p2[c];
        }
        float xv = (t < 64 && p < 512) ? bf2f((unsigned int)XT[p * 64 + b]) : 0.f;
        __syncthreads();
        if (t < 128) {
            bool active = (cell_l == 0) ? (p < 512) : (p >= 1);
            if (active) {
                float zi0 = bi0, zi1 = bi1, zj0 = bj0, zj1 = bj1;
                float zf0 = bf0, zf1 = bf1, zo0 = bo0, zo1 = bo1;
                #pragma unroll
                for (int ww = 0; ww < 8; ++ww) {
                    zi0 += red[cell_l][ww][0][b]; zi1 += red[cell_l][ww][1][b];
                    zj0 += red[cell_l][ww][2][b]; zj1 += red[cell_l][ww][3][b];
                    zf0 += red[cell_l][ww][4][b]; zf1 += red[cell_l][ww][5][b];
                    zo0 += red[cell_l][ww][6][b]; zo1 += red[cell_l][ww][7][b];
                }
                if (cell_l == 0) {
                    zi0 += xv * wxi0; zi1 += xv * wxi1;
                    zj0 += xv * wxj0; zj1 += xv * wxj1;
                    zf0 += xv * wxf0; zf1 += xv * wxf1;
                    zo0 += xv * wxo0; zo1 += xv * wxo1;
                }
                cs0 = cs0 * sigm(zf0 + 1.f) + sigm(zi0) * tanh_f(zj0);
                cs1 = cs1 * sigm(zf1 + 1.f) + sigm(zi1) * tanh_f(zj1);
                float h0 = tanh_f(cs0) * sigm(zo0);
                float h1 = tanh_f(cs1) * sigm(zo1);
                unsigned int packed = (unsigned int)f2bf(h0)
                                    | ((unsigned int)f2bf(h1) << 16);
                const int widx = (p + 1) & Rmask;
                unsigned int* dst = HHw + (widx * REGION_W + (bx >> 1) * 64 + b) * 4
                                  + cell_l * 2 + (bx & 1);
                __hip_atomic_store(dst, packed, __ATOMIC_RELAXED, __HIP_MEMORY_SCOPE_AGENT);
            }
        }
        grid_bar(BAR, p, bx, t);
    }
}

__global__ void logits_kernel(const char* __restrict__ wsb, const float* __restrict__ sw,
                              const float* __restrict__ sb, float* __restrict__ out) {
    // final h2 (step 511) written at phase 512 into region (513 % R) == 1 for R in {2,32}
    const unsigned int* HHr = (const unsigned int*)wsb;
    int c = blockIdx.x, b = threadIdx.x;
    float acc = 0.f;
    for (int k4 = 0; k4 < 128; ++k4) {
        int base = (REGION_W + k4 * 64 + b) * 4;
        unsigned int u = HHr[base + 2];
        unsigned int v = HHr[base + 3];
        acc += bf2f(u & 0xffffu) * sw[(4 * k4 + 0) * 10 + c];
        acc += bf2f(u >> 16)     * sw[(4 * k4 + 1) * 10 + c];
        acc += bf2f(v & 0xffffu) * sw[(4 * k4 + 2) * 10 + c];
        acc += bf2f(v >> 16)     * sw[(4 * k4 + 3) * 10 + c];
    }
    out[b * 10 + c] = acc + sb[c];
}

extern "C" void kernel_launch(void* const* d_in, const int* in_sizes, int n_in,
                              void* d_out, int out_size, void* d_ws, size_t ws_size,
                              hipStream_t stream) {
    (void)in_sizes; (void)n_in; (void)out_size;
    const float* x  = (const float*)d_in[0];
    const float* W0 = (const float*)d_in[1];
    const float* b0 = (const float*)d_in[2];
    const float* W1 = (const float*)d_in[3];
    const float* b1 = (const float*)d_in[4];
    const float* sw = (const float*)d_in[5];
    const float* sb = (const float*)d_in[6];
    char* wsb  = (char*)d_ws;
    float* out = (float*)d_out;

    const size_t REGION_BYTES = (size_t)REGION_W * 16;   // 139264
    const size_t need_ring = 32 * REGION_BYTES + 65536 + 36864 + 12582912; // 17,141,760
    int R = (ws_size >= need_ring) ? 32 : 2;
    int ring_mode = (R == 32) ? 1 : 0;
    int xt_off  = (int)(R * REGION_BYTES);
    int bar_off = xt_off + 65536;
    int wp_off  = bar_off + 36864;

    hipLaunchKernelGGL(init_kernel, dim3(1024), dim3(256), 0, stream,
                       x, W0, W1, wsb, R, xt_off, bar_off, wp_off);

    char* wsb_p = wsb;
    const float* W0_p = W0;
    const float* b0_p = b0;
    const float* b1_p = b1;
    int Rmask = R - 1;
    void* args[] = { &wsb_p, &W0_p, &b0_p, &b1_p, &Rmask, &ring_mode,
                     &xt_off, &bar_off, &wp_off };
    (void)hipLaunchCooperativeKernel((void*)lstm_kernel, dim3(256), dim3(512), args, 0, stream);

    hipLaunchKernelGGL(logits_kernel, dim3(10), dim3(64), 0, stream, wsb, sw, sb, out);
}

// Round 10
// 6711.242 us; speedup vs baseline: 1.9042x; 1.9042x over previous
//
#include <hip/hip_runtime.h>
#include <hip/hip_bf16.h>

// ws byte layout (12,976,128 B total — identical footprint to proven R7):
//   HH:  bf16 [2][128][64][8] @ 0      (262144 B)  h dbuf: per (k4,b) one 16B word =
//        {h1[4k4..4k4+3], h2[4k4..4k4+3]} — written via agent-scope atomic dword
//        stores (write-through to MALL; proven by R5-R7 correctness), read via
//        sc0-only loads (L1-bypass, L2-served) under the invalidation protocol.
//   XT:  bf16 [512][64]       @ 262144 (65536 B)  x transposed [t][b] (immutable)
//   BAR: @ 327680  ints, 128B-strided slots:
//        leaf[i]=BAR+i*32 (16 WGs/leaf) | root=BAR+16*32
//        xcnt[x]=BAR+(17+x)*32 (x=0..7) | xflag[x]=BAR+(25+x)*32
//   WP:  f32 [256][512][24] @ 393216 (12.58 MB) per-WG packed weights
//        (staging only — copied to LDS at kernel start)
#define HH_BYTES 0
#define XT_BYTES 262144
#define BAR_BYTES 327680
#define WP_BYTES 393216
#define BAR_INTS (33 * 32)

typedef __attribute__((ext_vector_type(4))) unsigned int uint4v;

__device__ __forceinline__ float sigm(float x) { return 1.f / (1.f + __expf(-x)); }
__device__ __forceinline__ float tanh_f(float x) {
    float a = fabsf(x);
    float e = __expf(-2.f * a);
    float r = (1.f - e) / (1.f + e);
    return copysignf(r, x);
}
__device__ __forceinline__ float bf2f(unsigned int u) {
    union { unsigned int i; float f; } v; v.i = u << 16; return v.f;
}
__device__ __forceinline__ unsigned short f2bf(float f) {
    union { float f; unsigned int i; } v; v.f = f;
    unsigned int u = v.i + 0x7fffu + ((v.i >> 16) & 1u);   // RNE
    return (unsigned short)(u >> 16);
}

__global__ void init_kernel(const float* __restrict__ x, const float* __restrict__ W0,
                            const float* __restrict__ W1, char* __restrict__ wsb) {
    unsigned int* Hz = (unsigned int*)(wsb + HH_BYTES);      // 65536 dwords
    unsigned short* XT = (unsigned short*)(wsb + XT_BYTES);
    int* BAR = (int*)(wsb + BAR_BYTES);
    float* WP = (float*)(wsb + WP_BYTES);
    int i = blockIdx.x * blockDim.x + threadIdx.x;
    int stride = gridDim.x * blockDim.x;
    for (int j = i; j < 65536; j += stride) Hz[j] = 0;
    for (int j = i; j < 32768; j += stride) {
        int p = j >> 6, b = j & 63;
        XT[j] = f2bf(x[b * 512 + p]);
    }
    for (int j = i; j < BAR_INTS; j += stride) BAR[j] = 0;
    for (int j = i; j < 256 * 512 * 24; j += stride) {
        int c = j % 24;
        int r = j / 24;            // bx*512 + k
        int k = r & 511;
        int bx = r >> 9;
        int cc = c & 7;
        int col = ((cc >> 1) << 9) + bx * 2 + (cc & 1);
        int mat = c >> 3;
        float v;
        if (mat == 0)      v = W0[(1 + k) * 2048 + col];
        else if (mat == 1) v = W1[k * 2048 + col];
        else               v = W1[(512 + k) * 2048 + col];
        WP[j] = v;
    }
}

__global__ __launch_bounds__(512) void lstm_kernel(char* __restrict__ wsb,
        const float* __restrict__ W0, const float* __restrict__ b0,
        const float* __restrict__ b1) {
    __shared__ float red[2][8][8][64];   // [layer][wave][c][b], 32 KB
    __shared__ float Wlds[512][24];      // per-WG weights, 48 KB

    const int t = threadIdx.x, bx = blockIdx.x;
    const int b = t & 63;
    const int w = __builtin_amdgcn_readfirstlane(t >> 6);    // wave id = k-slice owner

    int xcd;
    asm("s_getreg_b32 %0, hwreg(HW_REG_XCC_ID)" : "=s"(xcd));
    xcd &= 7;

    const uint4v* HH = (const uint4v*)(wsb + HH_BYTES);
    unsigned int* HHw = (unsigned int*)(wsb + HH_BYTES);
    const unsigned short* XT = (const unsigned short*)(wsb + XT_BYTES);
    int* BAR = (int*)(wsb + BAR_BYTES);
    int* leaf  = BAR + (bx >> 4) * 32;
    int* root  = BAR + 16 * 32;
    int* xcnt  = BAR + (17 + xcd) * 32;
    int* xflag = BAR + (25 + xcd) * 32;

    // ---- one-time: stage this WG's weights into LDS ----
    {
        const float* wpg = (const float*)(wsb + WP_BYTES) + bx * 12288;
        #pragma unroll
        for (int c = 0; c < 24; ++c) Wlds[t][c] = wpg[t * 24 + c];
    }

    // ---- one-time: per-XCD leader election (rank 0 on this XCD) ----
    int my_rank = 1 << 30;
    if (t == 0)
        my_rank = __hip_atomic_fetch_add(xcnt, 1, __ATOMIC_RELAXED, __HIP_MEMORY_SCOPE_AGENT);

    // cell threads: t<128 -> (layer l = t>>6, batch b); each computes BOTH hu of its pair
    const int cell_l = t >> 6;   // valid for t<128
    float cs0 = 0.f, cs1 = 0.f;
    float bi0 = 0, bi1 = 0, bj0 = 0, bj1 = 0, bf0 = 0, bf1 = 0, bo0 = 0, bo1 = 0;
    float wxi0 = 0, wxi1 = 0, wxj0 = 0, wxj1 = 0, wxf0 = 0, wxf1 = 0, wxo0 = 0, wxo1 = 0;
    if (t < 128) {
        int u0 = bx * 2, u1 = bx * 2 + 1;
        const float* bb = (cell_l == 0) ? b0 : b1;
        bi0 = bb[u0];            bi1 = bb[u1];
        bj0 = bb[512 + u0];      bj1 = bb[512 + u1];
        bf0 = bb[1024 + u0];     bf1 = bb[1024 + u1];
        bo0 = bb[1536 + u0];     bo1 = bb[1536 + u1];
        if (cell_l == 0) {
            wxi0 = W0[u0];          wxi1 = W0[u1];
            wxj0 = W0[512 + u0];    wxj1 = W0[512 + u1];
            wxf0 = W0[1024 + u0];   wxf1 = W0[1024 + u1];
            wxo0 = W0[1536 + u0];   wxo1 = W0[1536 + u1];
        }
    }
    __syncthreads();   // Wlds ready

    for (int p = 0; p <= 512; ++p) {
        // ---- h read: sc0 loads (L1-bypass), served by the XCD L2 which was
        //      invalidated+refilled-fresh under the barrier protocol ----
        const uint4v* hp = HH + (p & 1) * 8192 + w * 1024 + b;
        float p1[8] = {0, 0, 0, 0, 0, 0, 0, 0};
        float p2[8] = {0, 0, 0, 0, 0, 0, 0, 0};
        uint4v vv[16];
        #pragma unroll
        for (int i = 0; i < 16; ++i)
            asm volatile("global_load_dwordx4 %0, %1, off sc0"
                         : "=v"(vv[i]) : "v"(hp + i * 64));
        asm volatile("s_waitcnt vmcnt(0)" ::: "memory");

        #pragma unroll
        for (int i = 0; i < 16; ++i) {
            unsigned int x0 = vv[i].x, x1 = vv[i].y, x2 = vv[i].z, x3 = vv[i].w;
            float h1v[4] = { bf2f(x0 & 0xffffu), bf2f(x0 >> 16),
                             bf2f(x1 & 0xffffu), bf2f(x1 >> 16) };
            float h2v[4] = { bf2f(x2 & 0xffffu), bf2f(x2 >> 16),
                             bf2f(x3 & 0xffffu), bf2f(x3 >> 16) };
            #pragma unroll
            for (int j = 0; j < 4; ++j) {
                const float* wj = &Wlds[(w << 6) + (i << 2) + j][0];  // uniform -> broadcast
                #pragma unroll
                for (int c = 0; c < 8; ++c) {
                    p1[c] += wj[c] * h1v[j];
                    p2[c] += wj[8 + c] * h1v[j] + wj[16 + c] * h2v[j];
                }
            }
        }
        #pragma unroll
        for (int c = 0; c < 8; ++c) {
            red[0][w][c][b] = p1[c];
            red[1][w][c][b] = p2[c];
        }
        float xv = (t < 64 && p < 512) ? bf2f((unsigned int)XT[p * 64 + b]) : 0.f;
        __syncthreads();
        if (t < 128) {
            bool active = (cell_l == 0) ? (p < 512) : (p >= 1);
            if (active) {
                float zi0 = bi0, zi1 = bi1, zj0 = bj0, zj1 = bj1;
                float zf0 = bf0, zf1 = bf1, zo0 = bo0, zo1 = bo1;
                #pragma unroll
                for (int ww = 0; ww < 8; ++ww) {
                    zi0 += red[cell_l][ww][0][b]; zi1 += red[cell_l][ww][1][b];
                    zj0 += red[cell_l][ww][2][b]; zj1 += red[cell_l][ww][3][b];
                    zf0 += red[cell_l][ww][4][b]; zf1 += red[cell_l][ww][5][b];
                    zo0 += red[cell_l][ww][6][b]; zo1 += red[cell_l][ww][7][b];
                }
                if (cell_l == 0) {
                    zi0 += xv * wxi0; zi1 += xv * wxi1;
                    zj0 += xv * wxj0; zj1 += xv * wxj1;
                    zf0 += xv * wxf0; zf1 += xv * wxf1;
                    zo0 += xv * wxo0; zo1 += xv * wxo1;
                }
                cs0 = cs0 * sigm(zf0 + 1.f) + sigm(zi0) * tanh_f(zj0);
                cs1 = cs1 * sigm(zf1 + 1.f) + sigm(zi1) * tanh_f(zj1);
                float h0 = tanh_f(cs0) * sigm(zo0);
                float h1 = tanh_f(cs1) * sigm(zo1);
                unsigned int packed = (unsigned int)f2bf(h0)
                                    | ((unsigned int)f2bf(h1) << 16);
                unsigned int* dst = HHw + (((p + 1) & 1) * 8192 + (bx >> 1) * 64 + b) * 4
                                  + cell_l * 2 + (bx & 1);
                __hip_atomic_store(dst, packed, __ATOMIC_RELAXED, __HIP_MEMORY_SCOPE_AGENT);
            }
        }
        // ---- barrier + per-XCD L2 invalidation ----
        __syncthreads();                 // drains h stores (vmcnt 0 -> at MALL)
        if (t == 0) {
            int target = 16 * (p + 1);
            int old = __hip_atomic_fetch_add(leaf, 1, __ATOMIC_RELAXED, __HIP_MEMORY_SCOPE_AGENT);
            if (old == target - 1)
                __hip_atomic_fetch_add(root, 1, __ATOMIC_RELAXED, __HIP_MEMORY_SCOPE_AGENT);
            if (my_rank == 0) {          // this XCD's leader
                while (__hip_atomic_load(root, __ATOMIC_RELAXED, __HIP_MEMORY_SCOPE_AGENT) < target)
                    __builtin_amdgcn_s_sleep(1);
                __builtin_amdgcn_fence(__ATOMIC_ACQUIRE, "agent");  // buffer_inv sc1: L2 fresh
                __hip_atomic_store(xflag, p + 1, __ATOMIC_RELAXED, __HIP_MEMORY_SCOPE_AGENT);
            }
            while (__hip_atomic_load(xflag, __ATOMIC_RELAXED, __HIP_MEMORY_SCOPE_AGENT) < p + 1)
                __builtin_amdgcn_s_sleep(1);
        }
        __syncthreads();
    }
}

__global__ void logits_kernel(const char* __restrict__ wsb, const float* __restrict__ sw,
                              const float* __restrict__ sb, float* __restrict__ out) {
    const unsigned int* HHr = (const unsigned int*)(wsb + HH_BYTES);
    int c = blockIdx.x, b = threadIdx.x;
    float acc = 0.f;
    for (int k4 = 0; k4 < 128; ++k4) {
        int base = (8192 + k4 * 64 + b) * 4;       // buf 1 = h2[T-1]
        unsigned int u = HHr[base + 2];
        unsigned int v = HHr[base + 3];
        acc += bf2f(u & 0xffffu) * sw[(4 * k4 + 0) * 10 + c];
        acc += bf2f(u >> 16)     * sw[(4 * k4 + 1) * 10 + c];
        acc += bf2f(v & 0xffffu) * sw[(4 * k4 + 2) * 10 + c];
        acc += bf2f(v >> 16)     * sw[(4 * k4 + 3) * 10 + c];
    }
    out[b * 10 + c] = acc + sb[c];
}

extern "C" void kernel_launch(void* const* d_in, const int* in_sizes, int n_in,
                              void* d_out, int out_size, void* d_ws, size_t ws_size,
                              hipStream_t stream) {
    (void)in_sizes; (void)n_in; (void)out_size; (void)ws_size;
    const float* x  = (const float*)d_in[0];
    const float* W0 = (const float*)d_in[1];
    const float* b0 = (const float*)d_in[2];
    const float* W1 = (const float*)d_in[3];
    const float* b1 = (const float*)d_in[4];
    const float* sw = (const float*)d_in[5];
    const float* sb = (const float*)d_in[6];
    char* wsb  = (char*)d_ws;
    float* out = (float*)d_out;

    hipLaunchKernelGGL(init_kernel, dim3(1024), dim3(256), 0, stream, x, W0, W1, wsb);

    char* wsb_p = wsb;
    const float* W0_p = W0;
    const float* b0_p = b0;
    const float* b1_p = b1;
    void* args[] = { &wsb_p, &W0_p, &b0_p, &b1_p };
    (void)hipLaunchCooperativeKernel((void*)lstm_kernel, dim3(256), dim3(512), args, 0, stream);

    hipLaunchKernelGGL(logits_kernel, dim3(10), dim3(64), 0, stream, wsb, sw, sb, out);
}

// Round 12
// 3907.005 us; speedup vs baseline: 3.2710x; 1.7177x over previous
//
#include <hip/hip_runtime.h>
#include <hip/hip_bf16.h>

// ws byte layout (12,976,128 B total — identical to proven R7/R10 footprint):
//   HH:  bf16 [2][64 b][1024 k] @ 0 (262144 B)  h dbuf, row-major per batch:
//        k<512 = h1, k>=512 = h2 (stacked). Written via agent-scope atomic dword
//        stores (write-through to MALL; proven R5-R10), read via sc0 loads
//        (L1-bypass, L2-served) under the R10 leader-invalidation protocol.
//   XT:  bf16 [512][64] @ 262144 (65536 B)  x transposed [t][b] (immutable)
//   BAR: @ 327680: leaf[i]=+i*128 (16 WGs/leaf) | root=+16*128
//        xcnt[x]=+(17+x)*128 | xflag[x]=+(25+x)*128   (x = XCC_ID)
//   ZERO:@ 335872 (256 B zeros — B-frag source for z1 cols, k>=512 quadrant)
//   M1hi/M1lo: bf16 [2048 col][512 k]  @ 393216 / 2490368  (W0 recurrent, col-major)
//   M2hi/M2lo: bf16 [2048 col][1024 k] @ 4587520 / 8781824 (W1 full, col-major)
//   Weights live in REGISTERS during the loop (loaded once) -> L2 inv can't evict.
#define HH_B 0
#define XT_B 262144
#define BAR_B 327680
#define ZERO_B 335872
#define M1HI_B 393216
#define M1LO_B 2490368
#define M2HI_B 4587520
#define M2LO_B 8781824

typedef __attribute__((ext_vector_type(4))) unsigned int uint4v;
typedef __attribute__((ext_vector_type(8))) short short8;     // 8 bf16 (4 VGPRs)
typedef __attribute__((ext_vector_type(4))) float f32x4;
union AF { uint4v u; short8 s; };

__device__ __forceinline__ float sigm(float x) { return 1.f / (1.f + __expf(-x)); }
__device__ __forceinline__ float tanh_f(float x) {
    float a = fabsf(x);
    float e = __expf(-2.f * a);
    float r = (1.f - e) / (1.f + e);
    return copysignf(r, x);
}
__device__ __forceinline__ float bf2f(unsigned int u) {
    union { unsigned int i; float f; } v; v.i = u << 16; return v.f;
}
__device__ __forceinline__ unsigned short f2bf(float f) {
    union { float f; unsigned int i; } v; v.f = f;
    unsigned int u = v.i + 0x7fffu + ((v.i >> 16) & 1u);   // RNE
    return (unsigned short)(u >> 16);
}

__global__ void init_kernel(const float* __restrict__ x, const float* __restrict__ W0,
                            const float* __restrict__ W1, char* __restrict__ wsb) {
    unsigned int* Hz = (unsigned int*)(wsb + HH_B);          // 65536 dwords
    unsigned short* XT = (unsigned short*)(wsb + XT_B);
    int* BAR = (int*)(wsb + BAR_B);
    unsigned int* ZP = (unsigned int*)(wsb + ZERO_B);
    unsigned short* M1h = (unsigned short*)(wsb + M1HI_B);
    unsigned short* M1l = (unsigned short*)(wsb + M1LO_B);
    unsigned short* M2h = (unsigned short*)(wsb + M2HI_B);
    unsigned short* M2l = (unsigned short*)(wsb + M2LO_B);
    int i = blockIdx.x * blockDim.x + threadIdx.x;
    int stride = gridDim.x * blockDim.x;
    for (int j = i; j < 65536; j += stride) Hz[j] = 0;
    for (int j = i; j < 32768; j += stride) {
        int p = j >> 6, b = j & 63;
        XT[j] = f2bf(x[b * 512 + p]);
    }
    for (int j = i; j < 33 * 32; j += stride) BAR[j] = 0;
    for (int j = i; j < 64; j += stride) ZP[j] = 0;
    for (int j = i; j < 2048 * 512; j += stride) {           // M1: W0 recurrent rows 1..512
        int c = j >> 9, k = j & 511;
        float f = W0[(1 + k) * 2048 + c];
        unsigned short hi = f2bf(f);
        unsigned short lo = f2bf(f - bf2f(hi));
        M1h[c * 512 + k] = hi;  M1l[c * 512 + k] = lo;
    }
    for (int j = i; j < 2048 * 1024; j += stride) {          // M2: W1 full
        int c = j >> 10, k = j & 1023;
        float f = W1[k * 2048 + c];
        unsigned short hi = f2bf(f);
        unsigned short lo = f2bf(f - bf2f(hi));
        M2h[c * 1024 + k] = hi;  M2l[c * 1024 + k] = lo;
    }
}

__global__ __launch_bounds__(512) void lstm_kernel(char* __restrict__ wsb,
        const float* __restrict__ W0, const float* __restrict__ b0,
        const float* __restrict__ b1) {
    __shared__ float red[8 * 16 * 76];   // [wave][n][b], stride 76

    const int t = threadIdx.x, bx = blockIdx.x;
    const int b = t & 63;
    const int lane = t & 63;
    const int w = __builtin_amdgcn_readfirstlane(t >> 6);    // wave id = K-slice owner
    const int n = lane & 15, q = lane >> 4;

    int xcd;
    asm("s_getreg_b32 %0, hwreg(HW_REG_XCC_ID)" : "=s"(xcd));
    xcd &= 7;

    unsigned int* HHw = (unsigned int*)(wsb + HH_B);
    const unsigned short* XT = (const unsigned short*)(wsb + XT_B);
    int* BAR = (int*)(wsb + BAR_B);
    int* leaf  = BAR + (bx >> 4) * 32;
    int* root  = BAR + 16 * 32;
    int* xcnt  = BAR + (17 + xcd) * 32;
    int* xflag = BAR + (25 + xcd) * 32;

    // ---- one-time: B-frags (weights) into registers: hi+lo bf16 = exact fp32 ----
    short8 Bhi[4], Blo[4];
    {
        int nn = (n < 8) ? n : (n - 8);
        int colb = ((nn >> 1) << 9) + 2 * bx + (nn & 1);
        #pragma unroll
        for (int s = 0; s < 4; ++s) {
            int k_loc = w * 128 + s * 32 + q * 8;
            const short8 *phi, *plo;
            if (n < 8) {            // z1 cols: W0r for k<512, zero quadrant above
                if (k_loc < 512) {
                    phi = (const short8*)(wsb + M1HI_B + (colb * 512 + k_loc) * 2);
                    plo = (const short8*)(wsb + M1LO_B + (colb * 512 + k_loc) * 2);
                } else {
                    phi = (const short8*)(wsb + ZERO_B + q * 16);
                    plo = phi;
                }
            } else {                // z2 cols: W1 full K
                phi = (const short8*)(wsb + M2HI_B + (colb * 1024 + k_loc) * 2);
                plo = (const short8*)(wsb + M2LO_B + (colb * 1024 + k_loc) * 2);
            }
            Bhi[s] = *phi;  Blo[s] = *plo;
        }
    }

    // ---- one-time: per-XCD leader election (R10-proven) ----
    int my_rank = 1 << 30;
    if (t == 0)
        my_rank = __hip_atomic_fetch_add(xcnt, 1, __ATOMIC_RELAXED, __HIP_MEMORY_SCOPE_AGENT);

    // cell threads: t<128 -> (layer l = t>>6, batch b)
    const int cell_l = t >> 6;
    float cs0 = 0.f, cs1 = 0.f;
    float bi0 = 0, bi1 = 0, bj0 = 0, bj1 = 0, bf0 = 0, bf1 = 0, bo0 = 0, bo1 = 0;
    float wxi0 = 0, wxi1 = 0, wxj0 = 0, wxj1 = 0, wxf0 = 0, wxf1 = 0, wxo0 = 0, wxo1 = 0;
    if (t < 128) {
        int u0 = bx * 2, u1 = bx * 2 + 1;
        const float* bb = (cell_l == 0) ? b0 : b1;
        bi0 = bb[u0];            bi1 = bb[u1];
        bj0 = bb[512 + u0];      bj1 = bb[512 + u1];
        bf0 = bb[1024 + u0];     bf1 = bb[1024 + u1];
        bo0 = bb[1536 + u0];     bo1 = bb[1536 + u1];
        if (cell_l == 0) {
            wxi0 = W0[u0];          wxi1 = W0[u1];
            wxj0 = W0[512 + u0];    wxj1 = W0[512 + u1];
            wxf0 = W0[1024 + u0];   wxf1 = W0[1024 + u1];
            wxo0 = W0[1536 + u0];   wxo1 = W0[1536 + u1];
        }
    }

    // A-frag per-lane byte offset within a buffer: row (lane&15), k-slice (w,q)
    const int base_a = (lane & 15) * 2048 + w * 256 + q * 16;

    for (int p = 0; p <= 512; ++p) {
        // ---- A-frags: ONE asm block = 16 sc0 loads + waitcnt, early-clobber
        //      outputs. Compiler cannot copy/spill in-flight dest registers
        //      (the R11 NaN hazard), nor alias dests with address regs. ----
        const char* hb = wsb + (p & 1) * 131072 + base_a;
        const char* hr0 = hb;
        const char* hr1 = hb + 32768;
        const char* hr2 = hb + 65536;
        const char* hr3 = hb + 98304;
        uint4v av[4][4];
        asm volatile(
            "global_load_dwordx4 %0, %16, off sc0\n\t"
            "global_load_dwordx4 %1, %16, off offset:64 sc0\n\t"
            "global_load_dwordx4 %2, %16, off offset:128 sc0\n\t"
            "global_load_dwordx4 %3, %16, off offset:192 sc0\n\t"
            "global_load_dwordx4 %4, %17, off sc0\n\t"
            "global_load_dwordx4 %5, %17, off offset:64 sc0\n\t"
            "global_load_dwordx4 %6, %17, off offset:128 sc0\n\t"
            "global_load_dwordx4 %7, %17, off offset:192 sc0\n\t"
            "global_load_dwordx4 %8, %18, off sc0\n\t"
            "global_load_dwordx4 %9, %18, off offset:64 sc0\n\t"
            "global_load_dwordx4 %10, %18, off offset:128 sc0\n\t"
            "global_load_dwordx4 %11, %18, off offset:192 sc0\n\t"
            "global_load_dwordx4 %12, %19, off sc0\n\t"
            "global_load_dwordx4 %13, %19, off offset:64 sc0\n\t"
            "global_load_dwordx4 %14, %19, off offset:128 sc0\n\t"
            "global_load_dwordx4 %15, %19, off offset:192 sc0\n\t"
            "s_waitcnt vmcnt(0)"
            : "=&v"(av[0][0]), "=&v"(av[0][1]), "=&v"(av[0][2]), "=&v"(av[0][3]),
              "=&v"(av[1][0]), "=&v"(av[1][1]), "=&v"(av[1][2]), "=&v"(av[1][3]),
              "=&v"(av[2][0]), "=&v"(av[2][1]), "=&v"(av[2][2]), "=&v"(av[2][3]),
              "=&v"(av[3][0]), "=&v"(av[3][1]), "=&v"(av[3][2]), "=&v"(av[3][3])
            : "v"(hr0), "v"(hr1), "v"(hr2), "v"(hr3)
            : "memory");

        // ---- MFMA: D[64 b x 16 n] partial over this wave's K=128 slice ----
        f32x4 acc[4];
        #pragma unroll
        for (int mt = 0; mt < 4; ++mt) acc[mt] = (f32x4){0.f, 0.f, 0.f, 0.f};
        #pragma unroll
        for (int s = 0; s < 4; ++s) {
            #pragma unroll
            for (int mt = 0; mt < 4; ++mt) {
                AF af; af.u = av[mt][s];
                acc[mt] = __builtin_amdgcn_mfma_f32_16x16x32_bf16(af.s, Bhi[s], acc[mt], 0, 0, 0);
                acc[mt] = __builtin_amdgcn_mfma_f32_16x16x32_bf16(af.s, Blo[s], acc[mt], 0, 0, 0);
            }
        }
        // C layout: col n = lane&15, row b = mt*16 + q*4 + reg  ->  red[w][n][b]
        #pragma unroll
        for (int mt = 0; mt < 4; ++mt) {
            float* dst = red + (w * 16 + n) * 76 + mt * 16 + q * 4;
            *(f32x4*)dst = acc[mt];
        }
        float xv = (t < 64 && p < 512) ? bf2f((unsigned int)XT[p * 64 + b]) : 0.f;
        __syncthreads();
        // ---- cell update (t<128), publish h to MALL ----
        if (t < 128) {
            bool active = (cell_l == 0) ? (p < 512) : (p >= 1);
            if (active) {
                float zi0 = bi0, zi1 = bi1, zj0 = bj0, zj1 = bj1;
                float zf0 = bf0, zf1 = bf1, zo0 = bo0, zo1 = bo1;
                const int nb = cell_l * 8;
                #pragma unroll
                for (int ww = 0; ww < 8; ++ww) {
                    const float* rp = red + (ww * 16 + nb) * 76 + b;
                    zi0 += rp[0];        zi1 += rp[76];
                    zj0 += rp[2 * 76];   zj1 += rp[3 * 76];
                    zf0 += rp[4 * 76];   zf1 += rp[5 * 76];
                    zo0 += rp[6 * 76];   zo1 += rp[7 * 76];
                }
                if (cell_l == 0) {
                    zi0 += xv * wxi0; zi1 += xv * wxi1;
                    zj0 += xv * wxj0; zj1 += xv * wxj1;
                    zf0 += xv * wxf0; zf1 += xv * wxf1;
                    zo0 += xv * wxo0; zo1 += xv * wxo1;
                }
                cs0 = cs0 * sigm(zf0 + 1.f) + sigm(zi0) * tanh_f(zj0);
                cs1 = cs1 * sigm(zf1 + 1.f) + sigm(zi1) * tanh_f(zj1);
                float h0 = tanh_f(cs0) * sigm(zo0);
                float h1 = tanh_f(cs1) * sigm(zo1);
                unsigned int packed = (unsigned int)f2bf(h0)
                                    | ((unsigned int)f2bf(h1) << 16);
                // HST[b][k]: dword (b*512 + l*256 + bx) in buffer (p+1)&1
                unsigned int* dst = HHw + ((p + 1) & 1) * 32768 + b * 512
                                  + cell_l * 256 + bx;
                __hip_atomic_store(dst, packed, __ATOMIC_RELAXED, __HIP_MEMORY_SCOPE_AGENT);
            }
        }
        // ---- barrier + per-XCD L2 invalidation (R10-proven) ----
        __syncthreads();                 // drains h stores (vmcnt 0 -> at MALL)
        if (t == 0) {
            int target = 16 * (p + 1);
            int old = __hip_atomic_fetch_add(leaf, 1, __ATOMIC_RELAXED, __HIP_MEMORY_SCOPE_AGENT);
            if (old == target - 1)
                __hip_atomic_fetch_add(root, 1, __ATOMIC_RELAXED, __HIP_MEMORY_SCOPE_AGENT);
            if (my_rank == 0) {          // this XCD's leader
                while (__hip_atomic_load(root, __ATOMIC_RELAXED, __HIP_MEMORY_SCOPE_AGENT) < target)
                    __builtin_amdgcn_s_sleep(1);
                __builtin_amdgcn_fence(__ATOMIC_ACQUIRE, "agent");  // buffer_inv: L2 fresh
                __hip_atomic_store(xflag, p + 1, __ATOMIC_RELAXED, __HIP_MEMORY_SCOPE_AGENT);
            }
            while (__hip_atomic_load(xflag, __ATOMIC_RELAXED, __HIP_MEMORY_SCOPE_AGENT) < p + 1)
                __builtin_amdgcn_s_sleep(1);
        }
        __syncthreads();
    }
}

__global__ void logits_kernel(const char* __restrict__ wsb, const float* __restrict__ sw,
                              const float* __restrict__ sb, float* __restrict__ out) {
    // final h2 = h2[511], written at phase 512 into buffer 1, rows [b][512+k]
    const unsigned short* Hs = (const unsigned short*)(wsb + HH_B) + 65536;
    int c = blockIdx.x, b = threadIdx.x;
    float acc = 0.f;
    for (int k = 0; k < 512; ++k)
        acc += bf2f((unsigned int)Hs[b * 1024 + 512 + k]) * sw[k * 10 + c];
    out[b * 10 + c] = acc + sb[c];
}

extern "C" void kernel_launch(void* const* d_in, const int* in_sizes, int n_in,
                              void* d_out, int out_size, void* d_ws, size_t ws_size,
                              hipStream_t stream) {
    (void)in_sizes; (void)n_in; (void)out_size; (void)ws_size;
    const float* x  = (const float*)d_in[0];
    const float* W0 = (const float*)d_in[1];
    const float* b0 = (const float*)d_in[2];
    const float* W1 = (const float*)d_in[3];
    const float* b1 = (const float*)d_in[4];
    const float* sw = (const float*)d_in[5];
    const float* sb = (const float*)d_in[6];
    char* wsb  = (char*)d_ws;
    float* out = (float*)d_out;

    hipLaunchKernelGGL(init_kernel, dim3(1024), dim3(256), 0, stream, x, W0, W1, wsb);

    char* wsb_p = wsb;
    const float* W0_p = W0;
    const float* b0_p = b0;
    const float* b1_p = b1;
    void* args[] = { &wsb_p, &W0_p, &b0_p, &b1_p };
    (void)hipLaunchCooperativeKernel((void*)lstm_kernel, dim3(256), dim3(512), args, 0, stream);

    hipLaunchKernelGGL(logits_kernel, dim3(10), dim3(64), 0, stream, wsb, sw, sb, out);
}

// Round 13
// 3726.606 us; speedup vs baseline: 3.4293x; 1.0484x over previous
//
#include <hip/hip_runtime.h>
#include <hip/hip_bf16.h>

// ws byte layout (12,976,128 B — proven footprint):
//   REG0/REG1: bf16 [64 b][1024 k] @ 0 / 131072 — ring regions 0,1 (zero-init;
//              serve phases 0,1 before the weight area is recycled)
//   XT:  bf16 [512][64] @ 262144 (65536 B)  x transposed [t][b] (immutable)
//   BAR: @ 327680 (34944 B): leaf[i]=+i*128 (16 WGs/leaf) | root=+16*128
//        mail[w]=+(17+w)*128 (w=0..255)   — R6 fan-out barrier, epoch-monotone
//   ZERO:@ 366592 (256 B zeros — B-frag source for z1 cols, k>=512 quadrant)
//   WP/RING: @ 393216, 96 x 131072 = 12,582,912 B.
//        init_kernel stages hi/lo weights here (M1hi@+0, M1lo@+2097152,
//        M2hi@+4194304, M2lo@+8388608); lstm_kernel loads them into REGISTERS
//        pre-loop, then the SAME bytes become ring regions 2..97.
//   Ring: phase p reads region p%98 ({h1[p-1] k<512, h2[p-2] k>=512}, [b][1024k]),
//        writes region (p+1)%98 via agent-scope atomic dword stores (MALL
//        write-through, proven R5+). Readers use PLAIN cached loads: a region's
//        addresses were last written 98 phases ago; ~12.5 MB of fills churn each
//        4 MB 16-way L2 in between (128 KB region stride -> every set turns over
//        ~3x), so stale lines are structurally evicted. No fences, no buffer_inv.
#define XT_B 262144
#define BAR_B 327680
#define ZERO_B 366592
#define WP_B 393216
#define M1HI_B (WP_B + 0)
#define M1LO_B (WP_B + 2097152)
#define M2HI_B (WP_B + 4194304)
#define M2LO_B (WP_B + 8388608)
#define NREG 98
#define REG_BYTES 131072
#define BAR_INTS (273 * 32)
// final h2 (step 511) written at phase 512 -> region 513%98 = 23 -> base:
#define FINAL_REG_B (WP_B + (23 - 2) * REG_BYTES)   // = 3,145,728

typedef __attribute__((ext_vector_type(4))) unsigned int uint4v;
typedef __attribute__((ext_vector_type(8))) short short8;     // 8 bf16 (4 VGPRs)
typedef __attribute__((ext_vector_type(4))) float f32x4;
union AF { uint4v u; short8 s; };

__device__ __forceinline__ float sigm(float x) { return 1.f / (1.f + __expf(-x)); }
__device__ __forceinline__ float tanh_f(float x) {
    float a = fabsf(x);
    float e = __expf(-2.f * a);
    float r = (1.f - e) / (1.f + e);
    return copysignf(r, x);
}
__device__ __forceinline__ float bf2f(unsigned int u) {
    union { unsigned int i; float f; } v; v.i = u << 16; return v.f;
}
__device__ __forceinline__ unsigned short f2bf(float f) {
    union { float f; unsigned int i; } v; v.f = f;
    unsigned int u = v.i + 0x7fffu + ((v.i >> 16) & 1u);   // RNE
    return (unsigned short)(u >> 16);
}
__device__ __forceinline__ int reg_off(int r) {
    return (r < 2) ? r * REG_BYTES : WP_B + (r - 2) * REG_BYTES;
}

__global__ void init_kernel(const float* __restrict__ x, const float* __restrict__ W0,
                            const float* __restrict__ W1, char* __restrict__ wsb) {
    unsigned int* Hz = (unsigned int*)wsb;                   // regions 0,1 = 65536 dwords
    unsigned short* XT = (unsigned short*)(wsb + XT_B);
    int* BAR = (int*)(wsb + BAR_B);
    unsigned int* ZP = (unsigned int*)(wsb + ZERO_B);
    unsigned short* M1h = (unsigned short*)(wsb + M1HI_B);
    unsigned short* M1l = (unsigned short*)(wsb + M1LO_B);
    unsigned short* M2h = (unsigned short*)(wsb + M2HI_B);
    unsigned short* M2l = (unsigned short*)(wsb + M2LO_B);
    int i = blockIdx.x * blockDim.x + threadIdx.x;
    int stride = gridDim.x * blockDim.x;
    for (int j = i; j < 65536; j += stride) Hz[j] = 0;
    for (int j = i; j < 32768; j += stride) {
        int p = j >> 6, b = j & 63;
        XT[j] = f2bf(x[b * 512 + p]);
    }
    for (int j = i; j < BAR_INTS; j += stride) BAR[j] = 0;
    for (int j = i; j < 64; j += stride) ZP[j] = 0;
    for (int j = i; j < 2048 * 512; j += stride) {           // M1: W0 recurrent rows 1..512
        int c = j >> 9, k = j & 511;
        float f = W0[(1 + k) * 2048 + c];
        unsigned short hi = f2bf(f);
        unsigned short lo = f2bf(f - bf2f(hi));
        M1h[c * 512 + k] = hi;  M1l[c * 512 + k] = lo;
    }
    for (int j = i; j < 2048 * 1024; j += stride) {          // M2: W1 full
        int c = j >> 10, k = j & 1023;
        float f = W1[k * 2048 + c];
        unsigned short hi = f2bf(f);
        unsigned short lo = f2bf(f - bf2f(hi));
        M2h[c * 1024 + k] = hi;  M2l[c * 1024 + k] = lo;
    }
}

// R6 fan-out barrier (proven): leaf RMW -> root RMW -> broadcaster wave stores
// 256 per-WG mailboxes (1 poller/line). Epochs monotone. No fences needed: h
// stores are MALL write-through, drained (vmcnt 0) at __syncthreads before arrive.
__device__ __forceinline__ void grid_bar(int* bar, int epoch, int bx, int t) {
    __syncthreads();
    if (t < 64) {
        int* leaf = bar + (bx >> 4) * 32;
        int* root = bar + 16 * 32;
        int* mailbase = bar + 17 * 32;
        int target = 16 * (epoch + 1);
        int isB = 0;
        if (t == 0) {
            int old = __hip_atomic_fetch_add(leaf, 1, __ATOMIC_RELAXED, __HIP_MEMORY_SCOPE_AGENT);
            if (old == target - 1) {
                int ro = __hip_atomic_fetch_add(root, 1, __ATOMIC_RELAXED, __HIP_MEMORY_SCOPE_AGENT);
                if (ro == target - 1) isB = 1;
            }
        }
        isB = __builtin_amdgcn_readfirstlane(isB);
        if (isB) {
            #pragma unroll
            for (int r = 0; r < 4; ++r)
                __hip_atomic_store(mailbase + (r * 64 + t) * 32, epoch + 1,
                                   __ATOMIC_RELAXED, __HIP_MEMORY_SCOPE_AGENT);
        }
        if (t == 0) {
            int* my = mailbase + bx * 32;
            while (__hip_atomic_load(my, __ATOMIC_RELAXED, __HIP_MEMORY_SCOPE_AGENT) < epoch + 1)
                __builtin_amdgcn_s_sleep(1);
        }
    }
    __syncthreads();
}

__global__ __launch_bounds__(512) void lstm_kernel(char* __restrict__ wsb,
        const float* __restrict__ W0, const float* __restrict__ b0,
        const float* __restrict__ b1) {
    __shared__ float red[8 * 16 * 76];   // [wave][n][b], stride 76

    const int t = threadIdx.x, bx = blockIdx.x;
    const int b = t & 63;
    const int lane = t & 63;
    const int w = __builtin_amdgcn_readfirstlane(t >> 6);    // wave id = K-slice owner
    const int n = lane & 15, q = lane >> 4;

    const unsigned short* XT = (const unsigned short*)(wsb + XT_B);
    int* BAR = (int*)(wsb + BAR_B);

    // ---- one-time: B-frags (weights) into registers: hi+lo bf16 = exact fp32 ----
    short8 Bhi[4], Blo[4];
    {
        int nn = (n < 8) ? n : (n - 8);
        int colb = ((nn >> 1) << 9) + 2 * bx + (nn & 1);
        #pragma unroll
        for (int s = 0; s < 4; ++s) {
            int k_loc = w * 128 + s * 32 + q * 8;
            const short8 *phi, *plo;
            if (n < 8) {            // z1 cols: W0r for k<512, zero quadrant above
                if (k_loc < 512) {
                    phi = (const short8*)(wsb + M1HI_B + (colb * 512 + k_loc) * 2);
                    plo = (const short8*)(wsb + M1LO_B + (colb * 512 + k_loc) * 2);
                } else {
                    phi = (const short8*)(wsb + ZERO_B + q * 16);
                    plo = phi;
                }
            } else {                // z2 cols: W1 full K
                phi = (const short8*)(wsb + M2HI_B + (colb * 1024 + k_loc) * 2);
                plo = (const short8*)(wsb + M2LO_B + (colb * 1024 + k_loc) * 2);
            }
            Bhi[s] = *phi;  Blo[s] = *plo;
        }
    }
    // Pin B-frags in registers NOW: the staging bytes are recycled as ring
    // regions after the pre-loop barrier; the compiler must not sink the loads.
    asm volatile("" : "+v"(Bhi[0]), "+v"(Bhi[1]), "+v"(Bhi[2]), "+v"(Bhi[3]),
                      "+v"(Blo[0]), "+v"(Blo[1]), "+v"(Blo[2]), "+v"(Blo[3]) :: "memory");

    // cell threads: t<128 -> (layer l = t>>6, batch b)
    const int cell_l = t >> 6;
    float cs0 = 0.f, cs1 = 0.f;
    float bi0 = 0, bi1 = 0, bj0 = 0, bj1 = 0, bf0 = 0, bf1 = 0, bo0 = 0, bo1 = 0;
    float wxi0 = 0, wxi1 = 0, wxj0 = 0, wxj1 = 0, wxf0 = 0, wxf1 = 0, wxo0 = 0, wxo1 = 0;
    if (t < 128) {
        int u0 = bx * 2, u1 = bx * 2 + 1;
        const float* bb = (cell_l == 0) ? b0 : b1;
        bi0 = bb[u0];            bi1 = bb[u1];
        bj0 = bb[512 + u0];      bj1 = bb[512 + u1];
        bf0 = bb[1024 + u0];     bf1 = bb[1024 + u1];
        bo0 = bb[1536 + u0];     bo1 = bb[1536 + u1];
        if (cell_l == 0) {
            wxi0 = W0[u0];          wxi1 = W0[u1];
            wxj0 = W0[512 + u0];    wxj1 = W0[512 + u1];
            wxf0 = W0[1024 + u0];   wxf1 = W0[1024 + u1];
            wxo0 = W0[1536 + u0];   wxo1 = W0[1536 + u1];
        }
    }

    // Pre-loop grid barrier (epoch 0): all WGs have consumed the weight bytes.
    grid_bar(BAR, 0, bx, t);

    // A-frag per-lane byte offset within a region: row (lane&15), k-slice (w,q)
    const int base_a = (lane & 15) * 2048 + w * 256 + q * 16;

    int rd = 0;                       // read region = p % 98
    for (int p = 0; p <= 512; ++p) {
        const int wr = (rd + 1 == NREG) ? 0 : rd + 1;
        // ---- A-frags: PLAIN cached loads (ring freshness, no inv needed).
        //      One asm block: 16 loads + waitcnt, early-clobber (R12 NaN fix). ----
        const char* hb = wsb + reg_off(rd) + base_a;
        const char* hr0 = hb;
        const char* hr1 = hb + 32768;
        const char* hr2 = hb + 65536;
        const char* hr3 = hb + 98304;
        uint4v av[4][4];
        asm volatile(
            "global_load_dwordx4 %0, %16, off\n\t"
            "global_load_dwordx4 %1, %16, off offset:64\n\t"
            "global_load_dwordx4 %2, %16, off offset:128\n\t"
            "global_load_dwordx4 %3, %16, off offset:192\n\t"
            "global_load_dwordx4 %4, %17, off\n\t"
            "global_load_dwordx4 %5, %17, off offset:64\n\t"
            "global_load_dwordx4 %6, %17, off offset:128\n\t"
            "global_load_dwordx4 %7, %17, off offset:192\n\t"
            "global_load_dwordx4 %8, %18, off\n\t"
            "global_load_dwordx4 %9, %18, off offset:64\n\t"
            "global_load_dwordx4 %10, %18, off offset:128\n\t"
            "global_load_dwordx4 %11, %18, off offset:192\n\t"
            "global_load_dwordx4 %12, %19, off\n\t"
            "global_load_dwordx4 %13, %19, off offset:64\n\t"
            "global_load_dwordx4 %14, %19, off offset:128\n\t"
            "global_load_dwordx4 %15, %19, off offset:192\n\t"
            "s_waitcnt vmcnt(0)"
            : "=&v"(av[0][0]), "=&v"(av[0][1]), "=&v"(av[0][2]), "=&v"(av[0][3]),
              "=&v"(av[1][0]), "=&v"(av[1][1]), "=&v"(av[1][2]), "=&v"(av[1][3]),
              "=&v"(av[2][0]), "=&v"(av[2][1]), "=&v"(av[2][2]), "=&v"(av[2][3]),
              "=&v"(av[3][0]), "=&v"(av[3][1]), "=&v"(av[3][2]), "=&v"(av[3][3])
            : "v"(hr0), "v"(hr1), "v"(hr2), "v"(hr3)
            : "memory");

        // ---- MFMA: D[64 b x 16 n] partial over this wave's K=128 slice ----
        f32x4 acc[4];
        #pragma unroll
        for (int mt = 0; mt < 4; ++mt) acc[mt] = (f32x4){0.f, 0.f, 0.f, 0.f};
        #pragma unroll
        for (int s = 0; s < 4; ++s) {
            #pragma unroll
            for (int mt = 0; mt < 4; ++mt) {
                AF af; af.u = av[mt][s];
                acc[mt] = __builtin_amdgcn_mfma_f32_16x16x32_bf16(af.s, Bhi[s], acc[mt], 0, 0, 0);
                acc[mt] = __builtin_amdgcn_mfma_f32_16x16x32_bf16(af.s, Blo[s], acc[mt], 0, 0, 0);
            }
        }
        // C layout: col n = lane&15, row b = mt*16 + q*4 + reg  ->  red[w][n][b]
        #pragma unroll
        for (int mt = 0; mt < 4; ++mt) {
            float* dst = red + (w * 16 + n) * 76 + mt * 16 + q * 4;
            *(f32x4*)dst = acc[mt];
        }
        float xv = (t < 64 && p < 512) ? bf2f((unsigned int)XT[p * 64 + b]) : 0.f;
        __syncthreads();
        // ---- cell update (t<128), publish h to MALL (ring region wr) ----
        if (t < 128) {
            bool active = (cell_l == 0) ? (p < 512) : (p >= 1);
            if (active) {
                float zi0 = bi0, zi1 = bi1, zj0 = bj0, zj1 = bj1;
                float zf0 = bf0, zf1 = bf1, zo0 = bo0, zo1 = bo1;
                const int nb = cell_l * 8;
                #pragma unroll
                for (int ww = 0; ww < 8; ++ww) {
                    const float* rp = red + (ww * 16 + nb) * 76 + b;
                    zi0 += rp[0];        zi1 += rp[76];
                    zj0 += rp[2 * 76];   zj1 += rp[3 * 76];
                    zf0 += rp[4 * 76];   zf1 += rp[5 * 76];
                    zo0 += rp[6 * 76];   zo1 += rp[7 * 76];
                }
                if (cell_l == 0) {
                    zi0 += xv * wxi0; zi1 += xv * wxi1;
                    zj0 += xv * wxj0; zj1 += xv * wxj1;
                    zf0 += xv * wxf0; zf1 += xv * wxf1;
                    zo0 += xv * wxo0; zo1 += xv * wxo1;
                }
                cs0 = cs0 * sigm(zf0 + 1.f) + sigm(zi0) * tanh_f(zj0);
                cs1 = cs1 * sigm(zf1 + 1.f) + sigm(zi1) * tanh_f(zj1);
                float h0 = tanh_f(cs0) * sigm(zo0);
                float h1 = tanh_f(cs1) * sigm(zo1);
                unsigned int packed = (unsigned int)f2bf(h0)
                                    | ((unsigned int)f2bf(h1) << 16);
                unsigned int* dst = (unsigned int*)(wsb + reg_off(wr))
                                  + b * 512 + cell_l * 256 + bx;
                __hip_atomic_store(dst, packed, __ATOMIC_RELAXED, __HIP_MEMORY_SCOPE_AGENT);
            }
        }
        // ---- barrier (R6 fan-out; __syncthreads inside drains h stores) ----
        grid_bar(BAR, p + 1, bx, t);
        rd = wr;
    }
}

__global__ void logits_kernel(const char* __restrict__ wsb, const float* __restrict__ sw,
                              const float* __restrict__ sb, float* __restrict__ out) {
    // final h2 = h2[511], written at phase 512 -> region 23, rows [b][512+k]
    const unsigned short* Hs = (const unsigned short*)(wsb + FINAL_REG_B);
    int c = blockIdx.x, b = threadIdx.x;
    float acc = 0.f;
    for (int k = 0; k < 512; ++k)
        acc += bf2f((unsigned int)Hs[b * 1024 + 512 + k]) * sw[k * 10 + c];
    out[b * 10 + c] = acc + sb[c];
}

extern "C" void kernel_launch(void* const* d_in, const int* in_sizes, int n_in,
                              void* d_out, int out_size, void* d_ws, size_t ws_size,
                              hipStream_t stream) {
    (void)in_sizes; (void)n_in; (void)out_size; (void)ws_size;
    const float* x  = (const float*)d_in[0];
    const float* W0 = (const float*)d_in[1];
    const float* b0 = (const float*)d_in[2];
    const float* W1 = (const float*)d_in[3];
    const float* b1 = (const float*)d_in[4];
    const float* sw = (const float*)d_in[5];
    const float* sb = (const float*)d_in[6];
    char* wsb  = (char*)d_ws;
    float* out = (float*)d_out;

    hipLaunchKernelGGL(init_kernel, dim3(1024), dim3(256), 0, stream, x, W0, W1, wsb);

    char* wsb_p = wsb;
    const float* W0_p = W0;
    const float* b0_p = b0;
    const float* b1_p = b1;
    void* args[] = { &wsb_p, &W0_p, &b0_p, &b1_p };
    (void)hipLaunchCooperativeKernel((void*)lstm_kernel, dim3(256), dim3(512), args, 0, stream);

    hipLaunchKernelGGL(logits_kernel, dim3(10), dim3(64), 0, stream, wsb, sw, sb, out);
}